// Round 5
// baseline (275.233 us; speedup 1.0000x reference)
//
#include <hip/hip_runtime.h>
#include <hip/hip_bf16.h>

#define LN_EPS 1e-5f

typedef __attribute__((ext_vector_type(8))) short short8_t;
typedef __attribute__((ext_vector_type(4))) float float4_t;

__device__ __forceinline__ unsigned short f2bf(float x) {
    unsigned u = __builtin_bit_cast(unsigned, x);
    unsigned r = (u + 0x7FFFu + ((u >> 16) & 1u)) >> 16;
    return (unsigned short)r;
}

__device__ __forceinline__ float gelu_erf(float p) {
    return 0.5f * p * (1.0f + erff(p * 0.70710678118654752f));
}

// stage W^T (64 out-cols x 128 k) into swizzled LDS. 256 threads.
__device__ __forceinline__ void stage_w64(const float* __restrict__ W,
                                          unsigned short* Wbuf, int t) {
    const int c  = t & 63;
    const int kb = (t >> 6) * 32;
#pragma unroll
    for (int kk = 0; kk < 32; kk += 8) {
        unsigned short tmp[8];
#pragma unroll
        for (int i = 0; i < 8; ++i)
            tmp[i] = f2bf(W[(size_t)(kb + kk + i) * 64 + c]);
        unsigned idx = (unsigned)(c * 128 + kb + kk) ^ (unsigned)((c & 7) << 3);
        *(uint4*)&Wbuf[idx] = *(const uint4*)tmp;
    }
}

// ================= counting-sort pipeline (by dst) =================
__global__ __launch_bounds__(256) void hist_kernel(
    const int* __restrict__ dst, int* __restrict__ cnt, int E)
{
    const int i = blockIdx.x * blockDim.x + threadIdx.x;
    const int n = gridDim.x * blockDim.x;
    for (int e = i; e < E; e += n) atomicAdd(&cnt[dst[e]], 1);
}

// per-1024-chunk exclusive scan; block totals to bsum
__global__ __launch_bounds__(256) void scanA_kernel(
    const int* __restrict__ cnt, int* __restrict__ off,
    int* __restrict__ bsum, int n)
{
    __shared__ int ls[256];
    const int t = threadIdx.x;
    const int base = blockIdx.x * 1024 + t * 4;
    int v[4];
    int s = 0;
#pragma unroll
    for (int i = 0; i < 4; ++i) {
        v[i] = (base + i < n) ? cnt[base + i] : 0;
        s += v[i];
    }
    ls[t] = s;
    __syncthreads();
    for (int d = 1; d < 256; d <<= 1) {
        int x = (t >= d) ? ls[t - d] : 0;
        __syncthreads();
        ls[t] += x;
        __syncthreads();
    }
    int p = ls[t] - s;   // exclusive prefix for this thread's chunk
#pragma unroll
    for (int i = 0; i < 4; ++i) {
        if (base + i < n) off[base + i] = p;
        p += v[i];
    }
    if (t == 255) bsum[blockIdx.x] = ls[255];
}

// exclusive scan of <=64 block sums (single wave)
__global__ __launch_bounds__(64) void scanB_kernel(int* __restrict__ bsum, int nb)
{
    const int t = threadIdx.x;
    const int o = (t < nb) ? bsum[t] : 0;
    int v = o;
    for (int d = 1; d < 64; d <<= 1) {
        int x = __shfl_up(v, d);
        if (t >= d) v += x;
    }
    if (t < nb) bsum[t] = v - o;
}

__global__ __launch_bounds__(256) void scatter_kernel(
    const int* __restrict__ dst, int* __restrict__ off,
    const int* __restrict__ bsum, int* __restrict__ perm, int E)
{
    const int i = blockIdx.x * blockDim.x + threadIdx.x;
    const int n = gridDim.x * blockDim.x;
    for (int e = i; e < E; e += n) {
        const int d = dst[e];
        const int p = atomicAdd(&off[d], 1) + bsum[d >> 10];
        perm[p] = e;
    }
}

// ============ Kernel A: hv = LN(GELU(X @ W_node)) — barrier-free wave tiles ============
__global__ __launch_bounds__(256) void node_proj_kernel(
    const float* __restrict__ X, const float* __restrict__ W,
    const float* __restrict__ g, const float* __restrict__ b,
    float* __restrict__ out, int N)
{
    __shared__ __align__(16) unsigned short Wbuf[64 * 128];
    stage_w64(W, Wbuf, threadIdx.x);
    const int lane = threadIdx.x & 63;
    const int r16  = lane & 15;
    const int ks   = (lane >> 4) * 8;
    const int cq   = lane >> 4;
    float gv[4], bv[4];
#pragma unroll
    for (int ct = 0; ct < 4; ++ct) { gv[ct] = g[ct * 16 + r16]; bv[ct] = b[ct * 16 + r16]; }
    __syncthreads();

    const int gw = (int)((blockIdx.x * blockDim.x + threadIdx.x) >> 6);
    const int nw = (int)((gridDim.x * blockDim.x) >> 6);
    const int ntiles = (N + 15) >> 4;
    int tile = gw;
    if (tile >= ntiles) return;

    float4 pf[8];
    {
        const float* base = X + (size_t)min(tile * 16 + r16, N - 1) * 128;
#pragma unroll
        for (int kt = 0; kt < 4; ++kt) {
            pf[2 * kt]     = *(const float4*)(base + kt * 32 + ks);
            pf[2 * kt + 1] = *(const float4*)(base + kt * 32 + ks + 4);
        }
    }

    while (true) {
        const int r0 = tile * 16;
        short8_t a[4];
#pragma unroll
        for (int kt = 0; kt < 4; ++kt) {
            const float4 u = pf[2 * kt], v = pf[2 * kt + 1];
            short8_t t8;
            t8[0] = (short)f2bf(u.x); t8[1] = (short)f2bf(u.y);
            t8[2] = (short)f2bf(u.z); t8[3] = (short)f2bf(u.w);
            t8[4] = (short)f2bf(v.x); t8[5] = (short)f2bf(v.y);
            t8[6] = (short)f2bf(v.z); t8[7] = (short)f2bf(v.w);
            a[kt] = t8;
        }
        const int nt = tile + nw;
        if (nt < ntiles) {
            const float* base = X + (size_t)min(nt * 16 + r16, N - 1) * 128;
#pragma unroll
            for (int kt = 0; kt < 4; ++kt) {
                pf[2 * kt]     = *(const float4*)(base + kt * 32 + ks);
                pf[2 * kt + 1] = *(const float4*)(base + kt * 32 + ks + 4);
            }
        }

        float4_t acc[4];
#pragma unroll
        for (int ct = 0; ct < 4; ++ct) { acc[ct].x = 0.f; acc[ct].y = 0.f; acc[ct].z = 0.f; acc[ct].w = 0.f; }
#pragma unroll
        for (int ct = 0; ct < 4; ++ct) {
            const int c = ct * 16 + r16;
#pragma unroll
            for (int kt = 0; kt < 4; ++kt) {
                unsigned idx = (unsigned)(c * 128 + kt * 32 + ks) ^ (unsigned)((c & 7) << 3);
                short8_t bf = *(const short8_t*)&Wbuf[idx];
                acc[ct] = __builtin_amdgcn_mfma_f32_16x16x32_bf16(a[kt], bf, acc[ct], 0, 0, 0);
            }
        }

#pragma unroll
        for (int j = 0; j < 4; ++j) {
            float p0 = gelu_erf(acc[0][j]), p1 = gelu_erf(acc[1][j]);
            float p2 = gelu_erf(acc[2][j]), p3 = gelu_erf(acc[3][j]);
            float s = (p0 + p1) + (p2 + p3);
            s += __shfl_xor(s, 1); s += __shfl_xor(s, 2);
            s += __shfl_xor(s, 4); s += __shfl_xor(s, 8);
            const float mean = s * (1.0f / 64.0f);
            float d0 = p0 - mean, d1 = p1 - mean, d2 = p2 - mean, d3 = p3 - mean;
            float vs = d0 * d0 + d1 * d1 + d2 * d2 + d3 * d3;
            vs += __shfl_xor(vs, 1); vs += __shfl_xor(vs, 2);
            vs += __shfl_xor(vs, 4); vs += __shfl_xor(vs, 8);
            const float inv = rsqrtf(vs * (1.0f / 64.0f) + LN_EPS);
            const int r = r0 + cq * 4 + j;
            if (r < N) {
                float dd[4] = { d0, d1, d2, d3 };
#pragma unroll
                for (int ct = 0; ct < 4; ++ct)
                    out[(size_t)r * 64 + ct * 16 + r16] = dd[ct] * inv * gv[ct] + bv[ct];
            }
        }
        if (nt >= ntiles) break;
        tile = nt;
    }
}

// ============ Kernel B: edge — barrier-free, dst-sorted, run-merged scatter ============
__global__ __launch_bounds__(256) void edge_kernel(
    const float* __restrict__ EF, const float* __restrict__ W,
    const float* __restrict__ g, const float* __restrict__ b,
    const int* __restrict__ src, const int* __restrict__ dst,
    const int* __restrict__ perm,
    const float* __restrict__ hv, float* __restrict__ h, int E)
{
    __shared__ __align__(16) unsigned short Wbuf[64 * 128];
    __shared__ __align__(16) float mls[4][16 * 68];   // per-wave m tile, stride 68
    __shared__ int dstw[4][16];                       // per-wave sorted dsts
    stage_w64(W, Wbuf, threadIdx.x);
    const int lane = threadIdx.x & 63;
    const int r16  = lane & 15;
    const int ks   = (lane >> 4) * 8;
    const int cq   = lane >> 4;
    const int wv   = threadIdx.x >> 6;
    float gv[4], bv[4];
#pragma unroll
    for (int ct = 0; ct < 4; ++ct) { gv[ct] = g[ct * 16 + r16]; bv[ct] = b[ct * 16 + r16]; }
    __syncthreads();

    const int gw = (int)((blockIdx.x * blockDim.x + threadIdx.x) >> 6);
    const int nw = (int)((gridDim.x * blockDim.x) >> 6);
    const int ntiles = (E + 15) >> 4;
    int tile = gw;
    if (tile >= ntiles) return;

    // prologue: perm -> src/dst -> EF prefetch for first tile
    int pm, psrc, pdst;
    float4 pf[8];
    {
        pm   = perm[min(tile * 16 + r16, E - 1)];
        psrc = src[pm];
        pdst = dst[pm];
        const float* base = EF + (size_t)pm * 128;
#pragma unroll
        for (int kt = 0; kt < 4; ++kt) {
            pf[2 * kt]     = *(const float4*)(base + kt * 32 + ks);
            pf[2 * kt + 1] = *(const float4*)(base + kt * 32 + ks + 4);
        }
    }

    while (true) {
        const int e0 = tile * 16;
        const int nt = tile + nw;

        // issue next-tile perm load early
        int pmn = 0;
        if (nt < ntiles) pmn = perm[min(nt * 16 + r16, E - 1)];

        // hv gathers for current tile (sv via shfl of psrc)
        float hvv[4][4];
#pragma unroll
        for (int j = 0; j < 4; ++j) {
            const int svj = __shfl(psrc, cq * 4 + j);
#pragma unroll
            for (int ct = 0; ct < 4; ++ct)
                hvv[j][ct] = hv[(size_t)svj * 64 + ct * 16 + r16];
        }

        // publish this tile's sorted dsts
        if (lane < 16) dstw[wv][lane] = (e0 + lane < E) ? pdst : -1;

        // convert prefetched A rows
        short8_t a[4];
#pragma unroll
        for (int kt = 0; kt < 4; ++kt) {
            const float4 u = pf[2 * kt], v = pf[2 * kt + 1];
            short8_t t8;
            t8[0] = (short)f2bf(u.x); t8[1] = (short)f2bf(u.y);
            t8[2] = (short)f2bf(u.z); t8[3] = (short)f2bf(u.w);
            t8[4] = (short)f2bf(v.x); t8[5] = (short)f2bf(v.y);
            t8[6] = (short)f2bf(v.z); t8[7] = (short)f2bf(v.w);
            a[kt] = t8;
        }

        // prefetch next tile (EF rows + src/dst, via pmn)
        int psrcn = 0, pdstn = 0;
        if (nt < ntiles) {
            const float* base = EF + (size_t)pmn * 128;
#pragma unroll
            for (int kt = 0; kt < 4; ++kt) {
                pf[2 * kt]     = *(const float4*)(base + kt * 32 + ks);
                pf[2 * kt + 1] = *(const float4*)(base + kt * 32 + ks + 4);
            }
            psrcn = src[pmn];
            pdstn = dst[pmn];
        }

        float4_t acc[4];
#pragma unroll
        for (int ct = 0; ct < 4; ++ct) { acc[ct].x = 0.f; acc[ct].y = 0.f; acc[ct].z = 0.f; acc[ct].w = 0.f; }
#pragma unroll
        for (int ct = 0; ct < 4; ++ct) {
            const int c = ct * 16 + r16;
#pragma unroll
            for (int kt = 0; kt < 4; ++kt) {
                unsigned idx = (unsigned)(c * 128 + kt * 32 + ks) ^ (unsigned)((c & 7) << 3);
                short8_t bf = *(const short8_t*)&Wbuf[idx];
                acc[ct] = __builtin_amdgcn_mfma_f32_16x16x32_bf16(a[kt], bf, acc[ct], 0, 0, 0);
            }
        }

        // LN + exp + gather-mul -> wave-private LDS m tile
#pragma unroll
        for (int j = 0; j < 4; ++j) {
            float s = acc[0][j] + acc[1][j] + acc[2][j] + acc[3][j];
            s += __shfl_xor(s, 1); s += __shfl_xor(s, 2);
            s += __shfl_xor(s, 4); s += __shfl_xor(s, 8);
            const float mean = s * (1.0f / 64.0f);
            float d0 = acc[0][j] - mean, d1 = acc[1][j] - mean;
            float d2 = acc[2][j] - mean, d3 = acc[3][j] - mean;
            float vs = d0 * d0 + d1 * d1 + d2 * d2 + d3 * d3;
            vs += __shfl_xor(vs, 1); vs += __shfl_xor(vs, 2);
            vs += __shfl_xor(vs, 4); vs += __shfl_xor(vs, 8);
            const float inv = rsqrtf(vs * (1.0f / 64.0f) + LN_EPS);
            const bool ev = (e0 + cq * 4 + j) < E;
            float dd[4] = { d0, d1, d2, d3 };
#pragma unroll
            for (int ct = 0; ct < 4; ++ct) {
                const float he = __expf(dd[ct] * inv * gv[ct] + bv[ct]);
                mls[wv][(cq * 4 + j) * 68 + ct * 16 + r16] = ev ? he * hvv[j][ct] : 0.f;
            }
        }

        // wave-internal LDS visibility (producer == consumer wave)
        asm volatile("s_waitcnt lgkmcnt(0)" ::: "memory");

        // run-merged column reduction: lane owns col = lane; dst uniform per row
        {
            int cur = -1;
            float s = 0.f;
#pragma unroll
            for (int rr = 0; rr < 16; ++rr) {
                const int d   = dstw[wv][rr];
                const float v = mls[wv][rr * 68 + lane];
                if (d != cur) {
                    if (cur >= 0) atomicAdd(h + (size_t)cur * 64 + lane, s);
                    cur = d;
                    s = v;
                } else s += v;
            }
            if (cur >= 0) atomicAdd(h + (size_t)cur * 64 + lane, s);
        }

        if (nt >= ntiles) break;
        tile = nt;
        pm = pmn; psrc = psrcn; pdst = pdstn;
    }
}

// ============ Kernel C: out = LN(GELU(H @ W_out)) — K=64, 128 cols ============
__global__ __launch_bounds__(256) void out_proj_kernel(
    const float* __restrict__ Hin, const float* __restrict__ W,
    const float* __restrict__ g, const float* __restrict__ b,
    float* __restrict__ out, int N)
{
    __shared__ __align__(16) unsigned short Wbuf[128 * 64];
    {
        const int t  = threadIdx.x;
        const int c  = t & 127;
        const int k0 = (t >> 7) * 32;
#pragma unroll
        for (int kk = 0; kk < 32; kk += 8) {
            unsigned short tmp[8];
#pragma unroll
            for (int i = 0; i < 8; ++i)
                tmp[i] = f2bf(W[(size_t)(k0 + kk + i) * 128 + c]);
            unsigned idx = (unsigned)(c * 64 + k0 + kk) ^ (unsigned)((c & 7) << 3);
            *(uint4*)&Wbuf[idx] = *(const uint4*)tmp;
        }
    }
    const int lane = threadIdx.x & 63;
    const int r16  = lane & 15;
    const int ks   = (lane >> 4) * 8;
    const int cq   = lane >> 4;
    float gv[8], bv[8];
#pragma unroll
    for (int ct = 0; ct < 8; ++ct) { gv[ct] = g[ct * 16 + r16]; bv[ct] = b[ct * 16 + r16]; }
    __syncthreads();

    const int gw = (int)((blockIdx.x * blockDim.x + threadIdx.x) >> 6);
    const int nw = (int)((gridDim.x * blockDim.x) >> 6);
    const int ntiles = (N + 15) >> 4;
    int tile = gw;
    if (tile >= ntiles) return;

    float4 pf[4];
    {
        const float* base = Hin + (size_t)min(tile * 16 + r16, N - 1) * 64;
#pragma unroll
        for (int kt = 0; kt < 2; ++kt) {
            pf[2 * kt]     = *(const float4*)(base + kt * 32 + ks);
            pf[2 * kt + 1] = *(const float4*)(base + kt * 32 + ks + 4);
        }
    }

    while (true) {
        const int r0 = tile * 16;
        short8_t a[2];
#pragma unroll
        for (int kt = 0; kt < 2; ++kt) {
            const float4 u = pf[2 * kt], v = pf[2 * kt + 1];
            short8_t t8;
            t8[0] = (short)f2bf(u.x); t8[1] = (short)f2bf(u.y);
            t8[2] = (short)f2bf(u.z); t8[3] = (short)f2bf(u.w);
            t8[4] = (short)f2bf(v.x); t8[5] = (short)f2bf(v.y);
            t8[6] = (short)f2bf(v.z); t8[7] = (short)f2bf(v.w);
            a[kt] = t8;
        }
        const int nt = tile + nw;
        if (nt < ntiles) {
            const float* base = Hin + (size_t)min(nt * 16 + r16, N - 1) * 64;
#pragma unroll
            for (int kt = 0; kt < 2; ++kt) {
                pf[2 * kt]     = *(const float4*)(base + kt * 32 + ks);
                pf[2 * kt + 1] = *(const float4*)(base + kt * 32 + ks + 4);
            }
        }

        float4_t acc[8];
#pragma unroll
        for (int ct = 0; ct < 8; ++ct) { acc[ct].x = 0.f; acc[ct].y = 0.f; acc[ct].z = 0.f; acc[ct].w = 0.f; }
#pragma unroll
        for (int ct = 0; ct < 8; ++ct) {
            const int c = ct * 16 + r16;
#pragma unroll
            for (int kt = 0; kt < 2; ++kt) {
                unsigned idx = (unsigned)(c * 64 + kt * 32 + ks) ^ (unsigned)((c & 7) << 3);
                short8_t bf = *(const short8_t*)&Wbuf[idx];
                acc[ct] = __builtin_amdgcn_mfma_f32_16x16x32_bf16(a[kt], bf, acc[ct], 0, 0, 0);
            }
        }

#pragma unroll
        for (int j = 0; j < 4; ++j) {
            float p[8];
            float s = 0.f;
#pragma unroll
            for (int ct = 0; ct < 8; ++ct) { p[ct] = gelu_erf(acc[ct][j]); s += p[ct]; }
            s += __shfl_xor(s, 1); s += __shfl_xor(s, 2);
            s += __shfl_xor(s, 4); s += __shfl_xor(s, 8);
            const float mean = s * (1.0f / 128.0f);
            float vs = 0.f;
#pragma unroll
            for (int ct = 0; ct < 8; ++ct) { p[ct] -= mean; vs += p[ct] * p[ct]; }
            vs += __shfl_xor(vs, 1); vs += __shfl_xor(vs, 2);
            vs += __shfl_xor(vs, 4); vs += __shfl_xor(vs, 8);
            const float inv = rsqrtf(vs * (1.0f / 128.0f) + LN_EPS);
            const int r = r0 + cq * 4 + j;
            if (r < N) {
#pragma unroll
                for (int ct = 0; ct < 8; ++ct)
                    out[(size_t)r * 128 + ct * 16 + r16] = p[ct] * inv * gv[ct] + bv[ct];
            }
        }
        if (nt >= ntiles) break;
        tile = nt;
    }
}

extern "C" void kernel_launch(void* const* d_in, const int* in_sizes, int n_in,
                              void* d_out, int out_size, void* d_ws, size_t ws_size,
                              hipStream_t stream) {
    const float* node_feats = (const float*)d_in[0];
    const float* edge_feats = (const float*)d_in[1];
    const int*   src        = (const int*)d_in[2];
    const int*   dst        = (const int*)d_in[3];
    const float* W_node     = (const float*)d_in[4];
    const float* ln_ng      = (const float*)d_in[5];
    const float* ln_nb      = (const float*)d_in[6];
    const float* W_edge     = (const float*)d_in[7];
    const float* ln_eg      = (const float*)d_in[8];
    const float* ln_eb      = (const float*)d_in[9];
    const float* W_out      = (const float*)d_in[10];
    const float* ln_og      = (const float*)d_in[11];
    const float* ln_ob      = (const float*)d_in[12];
    float* out = (float*)d_out;

    const int N = in_sizes[0] / 128;
    const int E = in_sizes[2];

    float* hv   = (float*)d_ws;                 // N*64 f32
    float* h    = hv + (size_t)N * 64;          // N*64 f32
    int*   cnt  = (int*)(h + (size_t)N * 64);   // N
    int*   off  = cnt + N;                      // N
    int*   bsum = off + N;                      // <=64
    int*   perm = bsum + 64;                    // E

    const int nbA = (N + 1023) >> 10;           // scanA blocks (<=64)

    hipMemsetAsync(h, 0, (size_t)N * 64 * sizeof(float), stream);
    hipMemsetAsync(cnt, 0, (size_t)N * sizeof(int), stream);
    hist_kernel<<<1024, 256, 0, stream>>>(dst, cnt, E);
    scanA_kernel<<<nbA, 256, 0, stream>>>(cnt, off, bsum, N);
    scanB_kernel<<<1, 64, 0, stream>>>(bsum, nbA);
    scatter_kernel<<<1024, 256, 0, stream>>>(dst, off, bsum, perm, E);
    node_proj_kernel<<<784, 256, 0, stream>>>(node_feats, W_node, ln_ng, ln_nb, hv, N);
    edge_kernel<<<1024, 256, 0, stream>>>(edge_feats, W_edge, ln_eg, ln_eb,
                                          src, dst, perm, hv, h, E);
    out_proj_kernel<<<784, 256, 0, stream>>>(h, W_out, ln_og, ln_ob, out, N);
}